// Round 1
// baseline (4351.465 us; speedup 1.0000x reference)
//
#include <hip/hip_runtime.h>
#include <hip/hip_bf16.h>
#include <cmath>

// Problem: B=8, T=4096, D=1024.  M = B*T = 32768.
// Pipeline:
//   s[b,t]   = w2 . tanh(W1 x[b,t] + b1)            (b2 cancels in softmax)
//   e,den    = exp(s - max_b s), cumsum per batch
//   Y        = x @ Wc[:, :D]^T        (ws)
//   Z        = x @ Wc[:, D:]^T        (staged in d_out)
//   out[t]   = tanh( prefix(e*Y)[t]/den[t] + Z[t] + bc )
//
// ws layout (floats):
//   s:   [0, 32768)
//   e:   [32768, 65536)
//   den: [65536, 98304)
//   S:   [98304, 622592)          chunk partial sums, 8*64*1024
//   Y:   [622592, 622592+33554432)
// total ~130.4 MiB

#define Mtot 32768
#define Dd 1024
#define Tt 4096
#define Bb 8
#define TS 64
#define KC 64
#define NCHUNK 64   // chunks per batch
#define TCH 64      // t per chunk (NCHUNK*TCH = 4096)

// ---------------- GEMM 1: s = w2 . tanh(x @ W1^T + b1) ----------------
__global__ __launch_bounds__(256) void gemm_s(
    const float* __restrict__ x, const float* __restrict__ W1,
    const float* __restrict__ b1, const float* __restrict__ w2,
    float* __restrict__ s) {
  __shared__ float xs[TS][KC + 1];
  __shared__ float ws[TS][KC + 1];
  __shared__ float red[TS][17];
  int tid = threadIdx.x;
  int tx = tid & 15, ty = tid >> 4;
  int m0 = blockIdx.x * TS;
  int n0 = blockIdx.y * TS;
  float acc[4][4] = {};
  for (int k0 = 0; k0 < Dd; k0 += KC) {
#pragma unroll
    for (int i = 0; i < 16; ++i) {
      int idx = i * 256 + tid;
      int r = idx >> 6, c = idx & 63;
      xs[r][c] = x[(size_t)(m0 + r) * Dd + k0 + c];
      ws[r][c] = W1[(size_t)(n0 + r) * Dd + k0 + c];
    }
    __syncthreads();
#pragma unroll
    for (int k = 0; k < KC; ++k) {
      float a[4], b[4];
#pragma unroll
      for (int i = 0; i < 4; ++i) a[i] = xs[ty * 4 + i][k];
#pragma unroll
      for (int j = 0; j < 4; ++j) b[j] = ws[tx * 4 + j][k];
#pragma unroll
      for (int i = 0; i < 4; ++i)
#pragma unroll
        for (int j = 0; j < 4; ++j) acc[i][j] += a[i] * b[j];
    }
    __syncthreads();
  }
  // epilogue: tanh + dot with w2 over this n-tile, reduce across tx
  float pr[4];
#pragma unroll
  for (int i = 0; i < 4; ++i) {
    float p = 0.f;
#pragma unroll
    for (int j = 0; j < 4; ++j) {
      int n = n0 + tx * 4 + j;
      p += w2[n] * tanhf(acc[i][j] + b1[n]);
    }
    pr[i] = p;
  }
#pragma unroll
  for (int i = 0; i < 4; ++i) red[ty * 4 + i][tx] = pr[i];
  __syncthreads();
  if (tid < TS) {
    float v = 0.f;
#pragma unroll
    for (int j = 0; j < 16; ++j) v += red[tid][j];
    atomicAdd(&s[m0 + tid], v);
  }
}

// ---------------- softmax + cumsum(e) per batch ----------------
__global__ __launch_bounds__(256) void softmax_scan(
    const float* __restrict__ s, float* __restrict__ e, float* __restrict__ den) {
  int b = blockIdx.x, tid = threadIdx.x;
  const float* sb = s + (size_t)b * Tt;
  __shared__ float wsum[4], woff[4], redm[4];
  __shared__ float carry_s, total_s;
  int lane = tid & 63, wid = tid >> 6;
  float m = -1e30f;
  for (int i = tid; i < Tt; i += 256) m = fmaxf(m, sb[i]);
#pragma unroll
  for (int off = 32; off > 0; off >>= 1) m = fmaxf(m, __shfl_down(m, off, 64));
  if (lane == 0) redm[wid] = m;
  __syncthreads();
  if (tid == 0) {
    float mm = redm[0];
    for (int w = 1; w < 4; ++w) mm = fmaxf(mm, redm[w]);
    redm[0] = mm;
    carry_s = 0.f;
  }
  __syncthreads();
  m = redm[0];
  for (int c = 0; c < 16; ++c) {
    int t = c * 256 + tid;
    float v = expf(sb[t] - m);
    e[(size_t)b * Tt + t] = v;
    float sc = v;
#pragma unroll
    for (int off = 1; off < 64; off <<= 1) {
      float tt = __shfl_up(sc, off, 64);
      if (lane >= off) sc += tt;
    }
    if (lane == 63) wsum[wid] = sc;
    __syncthreads();
    if (tid == 0) {
      float a = 0.f;
      for (int w = 0; w < 4; ++w) { woff[w] = a; a += wsum[w]; }
      total_s = a;
    }
    __syncthreads();
    den[(size_t)b * Tt + t] = sc + woff[wid] + carry_s;
    __syncthreads();
    if (tid == 0) carry_s += total_s;
    __syncthreads();
  }
}

// ---------------- GEMM 2: Y = x@Wc_ctx^T ; Z = x@Wc_x^T (Z -> d_out) ----------------
__global__ __launch_bounds__(256) void gemm_yz(
    const float* __restrict__ x, const float* __restrict__ Wc,
    float* __restrict__ Y, float* __restrict__ Z) {
  __shared__ float xs[TS][KC + 1];
  __shared__ float ws[TS][KC + 1];
  int tid = threadIdx.x;
  int tx = tid & 15, ty = tid >> 4;
  int m0 = blockIdx.x * TS;
  int n0 = blockIdx.y * TS;          // 0..2047
  int half = n0 >> 10;               // 0 -> Y, 1 -> Z
  int n0c = n0 & 1023;
  const size_t wbase = (size_t)half * Dd;  // column offset into Wc rows
  float acc[4][4] = {};
  for (int k0 = 0; k0 < Dd; k0 += KC) {
#pragma unroll
    for (int i = 0; i < 16; ++i) {
      int idx = i * 256 + tid;
      int r = idx >> 6, c = idx & 63;
      xs[r][c] = x[(size_t)(m0 + r) * Dd + k0 + c];
      ws[r][c] = Wc[(size_t)(n0c + r) * (2 * Dd) + wbase + k0 + c];
    }
    __syncthreads();
#pragma unroll
    for (int k = 0; k < KC; ++k) {
      float a[4], b[4];
#pragma unroll
      for (int i = 0; i < 4; ++i) a[i] = xs[ty * 4 + i][k];
#pragma unroll
      for (int j = 0; j < 4; ++j) b[j] = ws[tx * 4 + j][k];
#pragma unroll
      for (int i = 0; i < 4; ++i)
#pragma unroll
        for (int j = 0; j < 4; ++j) acc[i][j] += a[i] * b[j];
    }
    __syncthreads();
  }
  float* dst = half ? Z : Y;
#pragma unroll
  for (int i = 0; i < 4; ++i) {
    int row = m0 + ty * 4 + i;
    float4 v = make_float4(acc[i][0], acc[i][1], acc[i][2], acc[i][3]);
    *(float4*)&dst[(size_t)row * Dd + n0c + tx * 4] = v;
  }
}

// ---------------- scan pass A: chunk partial sums ----------------
__global__ __launch_bounds__(1024) void chunk_sums(
    const float* __restrict__ Y, const float* __restrict__ e, float* __restrict__ S) {
  int bc = blockIdx.x;
  int b = bc >> 6, c = bc & 63;
  int d = threadIdx.x;
  const float* yb = Y + ((size_t)(b * Tt + c * TCH)) * Dd + d;
  const float* eb = e + (size_t)b * Tt + c * TCH;
  float acc = 0.f;
#pragma unroll 8
  for (int t = 0; t < TCH; ++t) acc += eb[t] * yb[(size_t)t * Dd];
  S[((size_t)bc) * Dd + d] = acc;
}

// ---------------- scan pass B: exclusive prefix over chunks ----------------
__global__ __launch_bounds__(256) void chunk_prefix(float* __restrict__ S) {
  int idx = blockIdx.x * 256 + threadIdx.x;  // over Bb*Dd = 8192
  int b = idx >> 10, d = idx & 1023;
  float* Sb = S + (size_t)b * NCHUNK * Dd + d;
  float acc = 0.f;
#pragma unroll 8
  for (int c = 0; c < NCHUNK; ++c) {
    float t = Sb[(size_t)c * Dd];
    Sb[(size_t)c * Dd] = acc;
    acc += t;
  }
}

// ---------------- scan pass C: finish prefix, divide, add Z + bc, tanh ----------------
__global__ __launch_bounds__(1024) void scan_out(
    const float* __restrict__ Y, const float* __restrict__ e,
    const float* __restrict__ den, const float* __restrict__ S,
    const float* __restrict__ bc_, float* __restrict__ out) {
  int bc = blockIdx.x;
  int b = bc >> 6, c = bc & 63;
  int d = threadIdx.x;
  int tbase = b * Tt + c * TCH;
  float acc = S[((size_t)bc) * Dd + d];
  float bias = bc_[d];
  const float* yb = Y + (size_t)tbase * Dd + d;
  const float* eb = e + tbase;
  const float* db = den + tbase;
  float* ob = out + (size_t)tbase * Dd + d;
#pragma unroll 4
  for (int t = 0; t < TCH; ++t) {
    acc += eb[t] * yb[(size_t)t * Dd];
    float z = ob[(size_t)t * Dd];
    ob[(size_t)t * Dd] = tanhf(acc / db[t] + z + bias);
  }
}

extern "C" void kernel_launch(void* const* d_in, const int* in_sizes, int n_in,
                              void* d_out, int out_size, void* d_ws, size_t ws_size,
                              hipStream_t stream) {
  const float* x  = (const float*)d_in[0];
  const float* W1 = (const float*)d_in[1];
  const float* b1 = (const float*)d_in[2];
  const float* w2 = (const float*)d_in[3];
  // d_in[4] = b2 : cancels under softmax shift invariance
  const float* Wc = (const float*)d_in[5];
  const float* bc = (const float*)d_in[6];
  float* out = (float*)d_out;

  float* ws = (float*)d_ws;
  float* s_buf   = ws;                       // 32768
  float* e_buf   = ws + 32768;               // 32768
  float* den_buf = ws + 65536;               // 32768
  float* S_buf   = ws + 98304;               // 8*64*1024 = 524288
  float* Y_buf   = ws + 622592;              // 33554432

  // s must start at zero (atomicAdd accumulation)
  hipMemsetAsync(s_buf, 0, (size_t)Mtot * sizeof(float), stream);

  dim3 blk(256);
  gemm_s<<<dim3(Mtot / TS, Dd / TS), blk, 0, stream>>>(x, W1, b1, w2, s_buf);
  softmax_scan<<<Bb, blk, 0, stream>>>(s_buf, e_buf, den_buf);
  gemm_yz<<<dim3(Mtot / TS, 2 * Dd / TS), blk, 0, stream>>>(x, Wc, Y_buf, out);
  chunk_sums<<<Bb * NCHUNK, 1024, 0, stream>>>(Y_buf, e_buf, S_buf);
  chunk_prefix<<<Bb * Dd / 256, 256, 0, stream>>>(S_buf);
  scan_out<<<Bb * NCHUNK, 1024, 0, stream>>>(Y_buf, e_buf, den_buf, S_buf, bc, out);
}

// Round 2
// 642.535 us; speedup vs baseline: 6.7723x; 6.7723x over previous
//
#include <hip/hip_runtime.h>
#include <cmath>

// B=8, T=4096, D=1024.  M = B*T = 32768.
// Pipeline:
//   cast x,W1,Wc -> bf16 (Wc repacked to [2048][1024] B^T form)
//   s[m]  = w2 . tanh(x @ W1^T + b1)        (MFMA, fused epilogue; b2 cancels)
//   e,den = exp(s - max), cumsum per batch
//   Y(bf16) = x @ Wc_ctx^T ; Z(fp32, in d_out) = x @ Wc_x^T   (one MFMA GEMM)
//   out = tanh( prefix(e*Y)/den + Z + bc )
//
// ws layout (float units):
//   s   [0, 32768)           e   [32768, 65536)       den [65536, 98304)
//   S   [98304, 622592)      Yb(bf16) [622592, 17399808)
//   xb(bf16) [17399808, 34177024)  W1b [34177024, 34701312)  Wcb [34701312, 35749888)
// total ~136.4 MiB

#define Mtot 32768
#define Dd 1024
#define Tt 4096
#define Bb 8
#define NCHUNK 64
#define TCH 64

typedef __bf16 bf16x8 __attribute__((ext_vector_type(8)));
typedef float f32x4 __attribute__((ext_vector_type(4)));

__device__ __forceinline__ unsigned short f2bf(float f) {
  unsigned int u = __float_as_uint(f);
  unsigned int r = (u + 0x7FFFu + ((u >> 16) & 1u)) >> 16;
  return (unsigned short)r;
}
__device__ __forceinline__ float bf2f(unsigned short s) {
  return __uint_as_float(((unsigned int)s) << 16);
}

__device__ __forceinline__ void gload16(const unsigned short* g, unsigned short* l) {
  __builtin_amdgcn_global_load_lds(
      (const __attribute__((address_space(1))) unsigned int*)g,
      (__attribute__((address_space(3))) unsigned int*)l, 16, 0, 0);
}

// ---------------- MFMA core: 128x128 tile, BK=64, 4 waves (2x2), XOR-swizzled LDS ----------------
__device__ __forceinline__ void mfma_core(
    const unsigned short* __restrict__ A, const unsigned short* __restrict__ W,
    int m0, int n0, unsigned short* As, unsigned short* Bs, f32x4 acc[4][4]) {
  int tid = threadIdx.x;
  int lane = tid & 63, w = tid >> 6;
  int wm = w >> 1, wn = w & 1;
  int quad = lane >> 4, c = lane & 15;
  int lrow = lane >> 3;          // 0..7 (row within 8-row staging group)
  int col8 = (lane & 7) ^ lrow;  // source column block after XOR swizzle

  for (int k0 = 0; k0 < Dd; k0 += 64) {
#pragma unroll
    for (int j = 0; j < 4; ++j) {
      int row = w * 32 + j * 8 + lrow;  // 0..127 within tile
      gload16(A + (size_t)(m0 + row) * Dd + k0 + col8 * 8, As + w * 2048 + j * 512);
      gload16(W + (size_t)(n0 + row) * Dd + k0 + col8 * 8, Bs + w * 2048 + j * 512);
    }
    __syncthreads();
#pragma unroll
    for (int ks = 0; ks < 2; ++ks) {
      bf16x8 af[4], bfr[4];
#pragma unroll
      for (int i = 0; i < 4; ++i) {
        int ra = wm * 64 + i * 16 + c;
        int pa = (ks * 4 + quad) ^ (ra & 7);
        af[i] = *(const bf16x8*)(As + ra * 64 + pa * 8);
        int rb = wn * 64 + i * 16 + c;
        int pb = (ks * 4 + quad) ^ (rb & 7);
        bfr[i] = *(const bf16x8*)(Bs + rb * 64 + pb * 8);
      }
#pragma unroll
      for (int i = 0; i < 4; ++i)
#pragma unroll
        for (int jn = 0; jn < 4; ++jn)
          acc[i][jn] = __builtin_amdgcn_mfma_f32_16x16x32_bf16(af[i], bfr[jn], acc[i][jn], 0, 0, 0);
    }
    __syncthreads();
  }
}

// ---------------- GEMM 1: s[m] = sum_n w2[n]*tanh((x@W1^T)[m][n] + b1[n]) ----------------
__global__ __launch_bounds__(256) void gemm_s(
    const unsigned short* __restrict__ xb, const unsigned short* __restrict__ W1b,
    const float* __restrict__ b1, const float* __restrict__ w2, float* __restrict__ s) {
  __shared__ unsigned short As[128 * 64];
  __shared__ unsigned short Bs[128 * 64];
  f32x4 acc[4][4];
#pragma unroll
  for (int i = 0; i < 4; ++i)
#pragma unroll
    for (int j = 0; j < 4; ++j) acc[i][j] = (f32x4){0.f, 0.f, 0.f, 0.f};
  int m0 = blockIdx.x * 128, n0 = blockIdx.y * 128;
  mfma_core(xb, W1b, m0, n0, As, Bs, acc);
  int tid = threadIdx.x, lane = tid & 63, w = tid >> 6;
  int wm = w >> 1, wn = w & 1, quad = lane >> 4, c = lane & 15;
#pragma unroll
  for (int i = 0; i < 4; ++i) {
#pragma unroll
    for (int r = 0; r < 4; ++r) {
      float p = 0.f;
#pragma unroll
      for (int jn = 0; jn < 4; ++jn) {
        int n = n0 + wn * 64 + jn * 16 + c;
        p += w2[n] * tanhf(acc[i][jn][r] + b1[n]);
      }
      p += __shfl_xor(p, 1, 64);
      p += __shfl_xor(p, 2, 64);
      p += __shfl_xor(p, 4, 64);
      p += __shfl_xor(p, 8, 64);
      if (c == 0) atomicAdd(&s[m0 + wm * 64 + i * 16 + quad * 4 + r], p);
    }
  }
}

// ---------------- GEMM 2: Y(bf16) = x@Wc_ctx^T ; Z(fp32->d_out) = x@Wc_x^T ----------------
__global__ __launch_bounds__(256) void gemm_yz(
    const unsigned short* __restrict__ xb, const unsigned short* __restrict__ Wcb,
    unsigned short* __restrict__ Yb, float* __restrict__ Z) {
  __shared__ unsigned short As[128 * 64];
  __shared__ unsigned short Bs[128 * 64];
  f32x4 acc[4][4];
#pragma unroll
  for (int i = 0; i < 4; ++i)
#pragma unroll
    for (int j = 0; j < 4; ++j) acc[i][j] = (f32x4){0.f, 0.f, 0.f, 0.f};
  int m0 = blockIdx.x * 128, n0 = blockIdx.y * 128;  // n0 in [0,2048)
  mfma_core(xb, Wcb, m0, n0, As, Bs, acc);
  int tid = threadIdx.x, lane = tid & 63, w = tid >> 6;
  int wm = w >> 1, wn = w & 1, quad = lane >> 4, c = lane & 15;
  int half = n0 >> 10, nc0 = n0 & 1023;
#pragma unroll
  for (int i = 0; i < 4; ++i)
#pragma unroll
    for (int jn = 0; jn < 4; ++jn)
#pragma unroll
      for (int r = 0; r < 4; ++r) {
        int m = m0 + wm * 64 + i * 16 + quad * 4 + r;
        int n = nc0 + wn * 64 + jn * 16 + c;
        float v = acc[i][jn][r];
        if (half == 0) Yb[(size_t)m * Dd + n] = f2bf(v);
        else           Z[(size_t)m * Dd + n] = v;
      }
}

// ---------------- casts ----------------
__global__ __launch_bounds__(256) void cast_x(const float4* __restrict__ x,
                                              ushort4* __restrict__ xb) {
  int i = blockIdx.x * 256 + threadIdx.x;  // over 33554432/4
  float4 v = x[i];
  ushort4 o;
  o.x = f2bf(v.x); o.y = f2bf(v.y); o.z = f2bf(v.z); o.w = f2bf(v.w);
  xb[i] = o;
}

// W1 [1024][1024] -> W1b ; Wc [1024][2048] -> Wcb packed [2048][1024]
__global__ __launch_bounds__(256) void cast_w(
    const float* __restrict__ W1, const float* __restrict__ Wc,
    ushort4* __restrict__ W1b, ushort4* __restrict__ Wcb) {
  int i = blockIdx.x * 256 + threadIdx.x;  // 786432 total
  if (i < 262144) {
    float4 v = ((const float4*)W1)[i];
    ushort4 o;
    o.x = f2bf(v.x); o.y = f2bf(v.y); o.z = f2bf(v.z); o.w = f2bf(v.w);
    W1b[i] = o;
  } else {
    int p = i - 262144;          // 0..524287
    int base = p * 4;
    int n = base >> 10, k = base & 1023;
    float4 v = *(const float4*)(Wc + (size_t)(n & 1023) * 2048 + (n >> 10) * 1024 + k);
    ushort4 o;
    o.x = f2bf(v.x); o.y = f2bf(v.y); o.z = f2bf(v.z); o.w = f2bf(v.w);
    Wcb[p] = o;
  }
}

// ---------------- softmax + cumsum(e) per batch ----------------
__global__ __launch_bounds__(256) void softmax_scan(
    const float* __restrict__ s, float* __restrict__ e, float* __restrict__ den) {
  int b = blockIdx.x, tid = threadIdx.x;
  const float* sb = s + (size_t)b * Tt;
  __shared__ float wsum[4], woff[4], redm[4];
  __shared__ float carry_s, total_s;
  int lane = tid & 63, wid = tid >> 6;
  float m = -1e30f;
  for (int i = tid; i < Tt; i += 256) m = fmaxf(m, sb[i]);
#pragma unroll
  for (int off = 32; off > 0; off >>= 1) m = fmaxf(m, __shfl_down(m, off, 64));
  if (lane == 0) redm[wid] = m;
  __syncthreads();
  if (tid == 0) {
    float mm = redm[0];
    for (int w = 1; w < 4; ++w) mm = fmaxf(mm, redm[w]);
    redm[0] = mm;
    carry_s = 0.f;
  }
  __syncthreads();
  m = redm[0];
  for (int c = 0; c < 16; ++c) {
    int t = c * 256 + tid;
    float v = expf(sb[t] - m);
    e[(size_t)b * Tt + t] = v;
    float sc = v;
#pragma unroll
    for (int off = 1; off < 64; off <<= 1) {
      float tt = __shfl_up(sc, off, 64);
      if (lane >= off) sc += tt;
    }
    if (lane == 63) wsum[wid] = sc;
    __syncthreads();
    if (tid == 0) {
      float a = 0.f;
      for (int w = 0; w < 4; ++w) { woff[w] = a; a += wsum[w]; }
      total_s = a;
    }
    __syncthreads();
    den[(size_t)b * Tt + t] = sc + woff[wid] + carry_s;
    __syncthreads();
    if (tid == 0) carry_s += total_s;
    __syncthreads();
  }
}

// ---------------- scan pass A: chunk partial sums ----------------
__global__ __launch_bounds__(1024) void chunk_sums(
    const unsigned short* __restrict__ Yb, const float* __restrict__ e,
    float* __restrict__ S) {
  int bc = blockIdx.x;
  int b = bc >> 6, c = bc & 63;
  int d = threadIdx.x;
  const unsigned short* yb = Yb + ((size_t)(b * Tt + c * TCH)) * Dd + d;
  const float* eb = e + (size_t)b * Tt + c * TCH;
  float acc = 0.f;
#pragma unroll 8
  for (int t = 0; t < TCH; ++t) acc += eb[t] * bf2f(yb[(size_t)t * Dd]);
  S[((size_t)bc) * Dd + d] = acc;
}

// ---------------- scan pass B: exclusive prefix over chunks ----------------
__global__ __launch_bounds__(256) void chunk_prefix(float* __restrict__ S) {
  int idx = blockIdx.x * 256 + threadIdx.x;  // over Bb*Dd = 8192
  int b = idx >> 10, d = idx & 1023;
  float* Sb = S + (size_t)b * NCHUNK * Dd + d;
  float acc = 0.f;
#pragma unroll 8
  for (int c = 0; c < NCHUNK; ++c) {
    float t = Sb[(size_t)c * Dd];
    Sb[(size_t)c * Dd] = acc;
    acc += t;
  }
}

// ---------------- scan pass C: finish prefix, divide, add Z + bc, tanh ----------------
__global__ __launch_bounds__(1024) void scan_out(
    const unsigned short* __restrict__ Yb, const float* __restrict__ e,
    const float* __restrict__ den, const float* __restrict__ S,
    const float* __restrict__ bc_, float* __restrict__ out) {
  int bc = blockIdx.x;
  int b = bc >> 6, c = bc & 63;
  int d = threadIdx.x;
  int tbase = b * Tt + c * TCH;
  float acc = S[((size_t)bc) * Dd + d];
  float bias = bc_[d];
  const unsigned short* yb = Yb + (size_t)tbase * Dd + d;
  const float* eb = e + tbase;
  const float* db = den + tbase;
  float* ob = out + (size_t)tbase * Dd + d;
#pragma unroll 4
  for (int t = 0; t < TCH; ++t) {
    acc += eb[t] * bf2f(yb[(size_t)t * Dd]);
    float z = ob[(size_t)t * Dd];
    ob[(size_t)t * Dd] = tanhf(acc / db[t] + z + bias);
  }
}

extern "C" void kernel_launch(void* const* d_in, const int* in_sizes, int n_in,
                              void* d_out, int out_size, void* d_ws, size_t ws_size,
                              hipStream_t stream) {
  const float* x  = (const float*)d_in[0];
  const float* W1 = (const float*)d_in[1];
  const float* b1 = (const float*)d_in[2];
  const float* w2 = (const float*)d_in[3];
  // d_in[4] = b2 : cancels under softmax shift invariance
  const float* Wc = (const float*)d_in[5];
  const float* bc = (const float*)d_in[6];
  float* out = (float*)d_out;

  float* ws = (float*)d_ws;
  float* s_buf   = ws;                       // 32768
  float* e_buf   = ws + 32768;               // 32768
  float* den_buf = ws + 65536;               // 32768
  float* S_buf   = ws + 98304;               // 524288
  unsigned short* Yb  = (unsigned short*)(ws + 622592);    // 33554432 bf16
  unsigned short* xb  = (unsigned short*)(ws + 17399808);  // 33554432 bf16
  unsigned short* W1b = (unsigned short*)(ws + 34177024);  // 1048576 bf16
  unsigned short* Wcb = (unsigned short*)(ws + 34701312);  // 2097152 bf16

  hipMemsetAsync(s_buf, 0, (size_t)Mtot * sizeof(float), stream);

  cast_x<<<32768, 256, 0, stream>>>((const float4*)x, (ushort4*)xb);
  cast_w<<<3072, 256, 0, stream>>>(W1, Wc, (ushort4*)W1b, (ushort4*)Wcb);

  gemm_s<<<dim3(Mtot / 128, Dd / 128), 256, 0, stream>>>(xb, W1b, b1, w2, s_buf);
  softmax_scan<<<Bb, 256, 0, stream>>>(s_buf, e_buf, den_buf);
  gemm_yz<<<dim3(Mtot / 128, 2 * Dd / 128), 256, 0, stream>>>(xb, Wcb, Yb, out);
  chunk_sums<<<Bb * NCHUNK, 1024, 0, stream>>>(Yb, e_buf, S_buf);
  chunk_prefix<<<Bb * Dd / 256, 256, 0, stream>>>(S_buf);
  scan_out<<<Bb * NCHUNK, 1024, 0, stream>>>(Yb, e_buf, den_buf, S_buf, bc, out);
}

// Round 3
// 579.721 us; speedup vs baseline: 7.5061x; 1.1084x over previous
//
#include <hip/hip_runtime.h>
#include <cmath>

// B=8, T=4096, D=1024.  M = B*T = 32768.
// Pipeline (uses linearity: prefix(e*(x@Wc_ctx^T)) = prefix(e*x)@Wc_ctx^T):
//   cast x->xb(bf16), W1->W1b, Wc->Wcb (native [1024][2048] layout = B^T)
//   s[m]  = w2 . tanh(xb @ W1b^T + b1)        (MFMA, fused epilogue; b2 cancels)
//   e,den = exp(s - max), cumsum per batch
//   q[t]  = prefix(e*x)[t]/den[t]  (bf16)     (3-pass chunked scan)
//   out   = tanh( [q|x] @ Wcb^T + bc )        (MFMA, K=2048, fused epilogue)
//
// ws layout (float units) — identical footprint to R1 (136.4 MiB):
//   s   [0, 32768)           e   [32768, 65536)       den [65536, 98304)
//   S   [98304, 622592)      qb(bf16) [622592, 17399808)
//   xb(bf16) [17399808, 34177024)  W1b [34177024, 34701312)  Wcb [34701312, 35749888)

#define Mtot 32768
#define Dd 1024
#define Tt 4096
#define Bb 8
#define NCHUNK 64
#define TCH 64

typedef __bf16 bf16x8 __attribute__((ext_vector_type(8)));
typedef float f32x4 __attribute__((ext_vector_type(4)));

__device__ __forceinline__ unsigned short f2bf(float f) {
  unsigned int u = __float_as_uint(f);
  unsigned int r = (u + 0x7FFFu + ((u >> 16) & 1u)) >> 16;
  return (unsigned short)r;
}
__device__ __forceinline__ float bf2f(unsigned short s) {
  return __uint_as_float(((unsigned int)s) << 16);
}

__device__ __forceinline__ void gload16(const unsigned short* g, unsigned short* l) {
  __builtin_amdgcn_global_load_lds(
      (const __attribute__((address_space(1))) unsigned int*)g,
      (__attribute__((address_space(3))) unsigned int*)l, 16, 0, 0);
}

// ---- MFMA core: 128x128 tile, BK=64, 4 waves (2x2), XOR-swizzled LDS ----
// A row-stride fixed 1024; source switches A0->A1 at k0>=1024 (for concat-K).
// W row-stride ldw, column index k0 (native layout).
__device__ __forceinline__ void mfma_core(
    const unsigned short* __restrict__ A0, const unsigned short* __restrict__ A1,
    const unsigned short* __restrict__ W, int ldw, int Ktot,
    int m0, int n0, unsigned short* As, unsigned short* Bs, f32x4 acc[4][4]) {
  int tid = threadIdx.x;
  int lane = tid & 63, w = tid >> 6;
  int wm = w >> 1, wn = w & 1;
  int quad = lane >> 4, c = lane & 15;
  int lrow = lane >> 3;          // 0..7 (row within 8-row staging group)
  int col8 = (lane & 7) ^ lrow;  // source column block after XOR swizzle

  for (int k0 = 0; k0 < Ktot; k0 += 64) {
    const unsigned short* Asrc = (k0 < 1024) ? A0 : A1;
    int ka = k0 & 1023;
#pragma unroll
    for (int j = 0; j < 4; ++j) {
      int row = w * 32 + j * 8 + lrow;  // 0..127 within tile
      gload16(Asrc + (size_t)(m0 + row) * 1024 + ka + col8 * 8, As + w * 2048 + j * 512);
      gload16(W + (size_t)(n0 + row) * ldw + k0 + col8 * 8, Bs + w * 2048 + j * 512);
    }
    __syncthreads();
#pragma unroll
    for (int ks = 0; ks < 2; ++ks) {
      bf16x8 af[4], bfr[4];
#pragma unroll
      for (int i = 0; i < 4; ++i) {
        int ra = wm * 64 + i * 16 + c;
        int pa = (ks * 4 + quad) ^ (ra & 7);
        af[i] = *(const bf16x8*)(As + ra * 64 + pa * 8);
        int rb = wn * 64 + i * 16 + c;
        int pb = (ks * 4 + quad) ^ (rb & 7);
        bfr[i] = *(const bf16x8*)(Bs + rb * 64 + pb * 8);
      }
#pragma unroll
      for (int i = 0; i < 4; ++i)
#pragma unroll
        for (int jn = 0; jn < 4; ++jn)
          acc[i][jn] = __builtin_amdgcn_mfma_f32_16x16x32_bf16(af[i], bfr[jn], acc[i][jn], 0, 0, 0);
    }
    __syncthreads();
  }
}

// ---- GEMM 1: s[m] = sum_n w2[n]*tanh((x@W1^T)[m][n] + b1[n]) ----
__global__ __launch_bounds__(256) void gemm_s(
    const unsigned short* __restrict__ xb, const unsigned short* __restrict__ W1b,
    const float* __restrict__ b1, const float* __restrict__ w2, float* __restrict__ s) {
  __shared__ unsigned short As[128 * 64];
  __shared__ unsigned short Bs[128 * 64];
  f32x4 acc[4][4];
#pragma unroll
  for (int i = 0; i < 4; ++i)
#pragma unroll
    for (int j = 0; j < 4; ++j) acc[i][j] = (f32x4){0.f, 0.f, 0.f, 0.f};
  int m0 = blockIdx.x * 128, n0 = blockIdx.y * 128;
  mfma_core(xb, xb, W1b, 1024, 1024, m0, n0, As, Bs, acc);
  int tid = threadIdx.x, lane = tid & 63, w = tid >> 6;
  int wm = w >> 1, wn = w & 1, quad = lane >> 4, c = lane & 15;
#pragma unroll
  for (int i = 0; i < 4; ++i) {
#pragma unroll
    for (int r = 0; r < 4; ++r) {
      float p = 0.f;
#pragma unroll
      for (int jn = 0; jn < 4; ++jn) {
        int n = n0 + wn * 64 + jn * 16 + c;
        p += w2[n] * tanhf(acc[i][jn][r] + b1[n]);
      }
      p += __shfl_xor(p, 1, 64);
      p += __shfl_xor(p, 2, 64);
      p += __shfl_xor(p, 4, 64);
      p += __shfl_xor(p, 8, 64);
      if (c == 0) atomicAdd(&s[m0 + wm * 64 + i * 16 + quad * 4 + r], p);
    }
  }
}

// ---- GEMM 2: out = tanh([q|x] @ Wc^T + bc), K=2048 ----
__global__ __launch_bounds__(256) void gemm_out(
    const unsigned short* __restrict__ qb, const unsigned short* __restrict__ xb,
    const unsigned short* __restrict__ Wcb, const float* __restrict__ bc_,
    float* __restrict__ out) {
  __shared__ unsigned short As[128 * 64];
  __shared__ unsigned short Bs[128 * 64];
  f32x4 acc[4][4];
#pragma unroll
  for (int i = 0; i < 4; ++i)
#pragma unroll
    for (int j = 0; j < 4; ++j) acc[i][j] = (f32x4){0.f, 0.f, 0.f, 0.f};
  int m0 = blockIdx.x * 128, n0 = blockIdx.y * 128;
  mfma_core(qb, xb, Wcb, 2048, 2048, m0, n0, As, Bs, acc);
  int tid = threadIdx.x, lane = tid & 63, w = tid >> 6;
  int wm = w >> 1, wn = w & 1, quad = lane >> 4, c = lane & 15;
#pragma unroll
  for (int i = 0; i < 4; ++i)
#pragma unroll
    for (int jn = 0; jn < 4; ++jn) {
      int n = n0 + wn * 64 + jn * 16 + c;
      float bias = bc_[n];
#pragma unroll
      for (int r = 0; r < 4; ++r) {
        int m = m0 + wm * 64 + i * 16 + quad * 4 + r;
        out[(size_t)m * Dd + n] = tanhf(acc[i][jn][r] + bias);
      }
    }
}

// ---- casts ----
__global__ __launch_bounds__(256) void cast_x(const float4* __restrict__ x,
                                              ushort4* __restrict__ xb) {
  int i = blockIdx.x * 256 + threadIdx.x;  // over 33554432/4
  float4 v = x[i];
  ushort4 o;
  o.x = f2bf(v.x); o.y = f2bf(v.y); o.z = f2bf(v.z); o.w = f2bf(v.w);
  xb[i] = o;
}

// W1 [1024][1024] -> W1b ; Wc [1024][2048] -> Wcb (straight cast, native layout)
__global__ __launch_bounds__(256) void cast_w(
    const float* __restrict__ W1, const float* __restrict__ Wc,
    ushort4* __restrict__ W1b, ushort4* __restrict__ Wcb) {
  int i = blockIdx.x * 256 + threadIdx.x;  // 786432 total
  if (i < 262144) {
    float4 v = ((const float4*)W1)[i];
    ushort4 o;
    o.x = f2bf(v.x); o.y = f2bf(v.y); o.z = f2bf(v.z); o.w = f2bf(v.w);
    W1b[i] = o;
  } else {
    int p = i - 262144;  // 0..524287 over Wc/4
    float4 v = ((const float4*)Wc)[p];
    ushort4 o;
    o.x = f2bf(v.x); o.y = f2bf(v.y); o.z = f2bf(v.z); o.w = f2bf(v.w);
    Wcb[p] = o;
  }
}

// ---- softmax + cumsum(e) per batch ----
__global__ __launch_bounds__(256) void softmax_scan(
    const float* __restrict__ s, float* __restrict__ e, float* __restrict__ den) {
  int b = blockIdx.x, tid = threadIdx.x;
  const float* sb = s + (size_t)b * Tt;
  __shared__ float wsum[4], woff[4], redm[4];
  __shared__ float carry_s, total_s;
  int lane = tid & 63, wid = tid >> 6;
  float m = -1e30f;
  for (int i = tid; i < Tt; i += 256) m = fmaxf(m, sb[i]);
#pragma unroll
  for (int off = 32; off > 0; off >>= 1) m = fmaxf(m, __shfl_down(m, off, 64));
  if (lane == 0) redm[wid] = m;
  __syncthreads();
  if (tid == 0) {
    float mm = redm[0];
    for (int w = 1; w < 4; ++w) mm = fmaxf(mm, redm[w]);
    redm[0] = mm;
    carry_s = 0.f;
  }
  __syncthreads();
  m = redm[0];
  for (int c = 0; c < 16; ++c) {
    int t = c * 256 + tid;
    float v = expf(sb[t] - m);
    e[(size_t)b * Tt + t] = v;
    float sc = v;
#pragma unroll
    for (int off = 1; off < 64; off <<= 1) {
      float tt = __shfl_up(sc, off, 64);
      if (lane >= off) sc += tt;
    }
    if (lane == 63) wsum[wid] = sc;
    __syncthreads();
    if (tid == 0) {
      float a = 0.f;
      for (int w = 0; w < 4; ++w) { woff[w] = a; a += wsum[w]; }
      total_s = a;
    }
    __syncthreads();
    den[(size_t)b * Tt + t] = sc + woff[wid] + carry_s;
    __syncthreads();
    if (tid == 0) carry_s += total_s;
    __syncthreads();
  }
}

// ---- scan pass A: chunk partial sums of e*x ----
__global__ __launch_bounds__(1024) void chunk_sums(
    const unsigned short* __restrict__ xb, const float* __restrict__ e,
    float* __restrict__ S) {
  int bc = blockIdx.x;
  int b = bc >> 6, c = bc & 63;
  int d = threadIdx.x;
  const unsigned short* xp = xb + ((size_t)(b * Tt + c * TCH)) * Dd + d;
  const float* eb = e + (size_t)b * Tt + c * TCH;
  float acc = 0.f;
#pragma unroll 8
  for (int t = 0; t < TCH; ++t) acc += eb[t] * bf2f(xp[(size_t)t * Dd]);
  S[((size_t)bc) * Dd + d] = acc;
}

// ---- scan pass B: exclusive prefix over chunks ----
__global__ __launch_bounds__(256) void chunk_prefix(float* __restrict__ S) {
  int idx = blockIdx.x * 256 + threadIdx.x;  // over Bb*Dd = 8192
  int b = idx >> 10, d = idx & 1023;
  float* Sb = S + (size_t)b * NCHUNK * Dd + d;
  float acc = 0.f;
#pragma unroll 8
  for (int c = 0; c < NCHUNK; ++c) {
    float t = Sb[(size_t)c * Dd];
    Sb[(size_t)c * Dd] = acc;
    acc += t;
  }
}

// ---- scan pass C: finish prefix, q = prefix(e*x)/den -> bf16 ----
__global__ __launch_bounds__(1024) void scan_q(
    const unsigned short* __restrict__ xb, const float* __restrict__ e,
    const float* __restrict__ den, const float* __restrict__ S,
    unsigned short* __restrict__ qb) {
  int bc = blockIdx.x;
  int b = bc >> 6, c = bc & 63;
  int d = threadIdx.x;
  int tbase = b * Tt + c * TCH;
  float acc = S[((size_t)bc) * Dd + d];
  const unsigned short* xp = xb + (size_t)tbase * Dd + d;
  const float* eb = e + tbase;
  const float* db = den + tbase;
  unsigned short* qp = qb + (size_t)tbase * Dd + d;
#pragma unroll 4
  for (int t = 0; t < TCH; ++t) {
    acc += eb[t] * bf2f(xp[(size_t)t * Dd]);
    qp[(size_t)t * Dd] = f2bf(acc / db[t]);
  }
}

extern "C" void kernel_launch(void* const* d_in, const int* in_sizes, int n_in,
                              void* d_out, int out_size, void* d_ws, size_t ws_size,
                              hipStream_t stream) {
  const float* x  = (const float*)d_in[0];
  const float* W1 = (const float*)d_in[1];
  const float* b1 = (const float*)d_in[2];
  const float* w2 = (const float*)d_in[3];
  // d_in[4] = b2 : cancels under softmax shift invariance
  const float* Wc = (const float*)d_in[5];
  const float* bc = (const float*)d_in[6];
  float* out = (float*)d_out;

  float* ws = (float*)d_ws;
  float* s_buf   = ws;                       // 32768
  float* e_buf   = ws + 32768;               // 32768
  float* den_buf = ws + 65536;               // 32768
  float* S_buf   = ws + 98304;               // 524288
  unsigned short* qb  = (unsigned short*)(ws + 622592);    // 33554432 bf16
  unsigned short* xb  = (unsigned short*)(ws + 17399808);  // 33554432 bf16
  unsigned short* W1b = (unsigned short*)(ws + 34177024);  // 1048576 bf16
  unsigned short* Wcb = (unsigned short*)(ws + 34701312);  // 2097152 bf16

  hipMemsetAsync(s_buf, 0, (size_t)Mtot * sizeof(float), stream);

  cast_x<<<32768, 256, 0, stream>>>((const float4*)x, (ushort4*)xb);
  cast_w<<<3072, 256, 0, stream>>>(W1, Wc, (ushort4*)W1b, (ushort4*)Wcb);

  gemm_s<<<dim3(Mtot / 128, Dd / 128), 256, 0, stream>>>(xb, W1b, b1, w2, s_buf);
  softmax_scan<<<Bb, 256, 0, stream>>>(s_buf, e_buf, den_buf);
  chunk_sums<<<Bb * NCHUNK, 1024, 0, stream>>>(xb, e_buf, S_buf);
  chunk_prefix<<<Bb * Dd / 256, 256, 0, stream>>>(S_buf);
  scan_q<<<Bb * NCHUNK, 1024, 0, stream>>>(xb, e_buf, den_buf, S_buf, qb);
  gemm_out<<<dim3(Mtot / 128, Dd / 128), 256, 0, stream>>>(qb, xb, Wcb, bc, out);
}

// Round 4
// 535.642 us; speedup vs baseline: 8.1238x; 1.0823x over previous
//
#include <hip/hip_runtime.h>
#include <cmath>

// B=8, T=4096, D=1024.  M = B*T = 32768.
// Pipeline (uses linearity: prefix(e*(x@Wc_ctx^T)) = prefix(e*x)@Wc_ctx^T):
//   cast_all: x->xb(bf16), W1->W1b, Wc->Wcb (native layout), s:=0
//   s[m]  = w2 . tanh(xb @ W1b^T + b1)        (MFMA, fused epilogue; b2 cancels)
//   e,den = exp(s - max), cumsum per batch    (single-pass block scan)
//   q[t]  = prefix(e*x)[t]/den[t]  (bf16)     (3-pass chunked scan)
//   out   = tanh( [q|x] @ Wcb^T + bc )        (MFMA, K=2048, fused epilogue)
//
// ws layout (float units):
//   s   [0, 32768)           e   [32768, 65536)       den [65536, 98304)
//   S   [98304, 622592)      qb(bf16) [622592, 17399808)
//   xb(bf16) [17399808, 34177024)  W1b [34177024, 34701312)  Wcb [34701312, 35749888)

#define Mtot 32768
#define Dd 1024
#define Tt 4096
#define Bb 8
#define NCHUNK 64
#define TCH 64

typedef __bf16 bf16x8 __attribute__((ext_vector_type(8)));
typedef float f32x4 __attribute__((ext_vector_type(4)));

__device__ __forceinline__ unsigned short f2bf(float f) {
  unsigned int u = __float_as_uint(f);
  unsigned int r = (u + 0x7FFFu + ((u >> 16) & 1u)) >> 16;
  return (unsigned short)r;
}
__device__ __forceinline__ float bf2f(unsigned short s) {
  return __uint_as_float(((unsigned int)s) << 16);
}
// fast tanh: 1 - 2/(e^{2x}+1)   (v_exp_f32 + fast div; rel err ~1e-6)
__device__ __forceinline__ float tanh_fast(float x) {
  return 1.0f - __fdividef(2.0f, __expf(2.0f * x) + 1.0f);
}

__device__ __forceinline__ void gload16(const unsigned short* g, unsigned short* l) {
  __builtin_amdgcn_global_load_lds(
      (const __attribute__((address_space(1))) unsigned int*)g,
      (__attribute__((address_space(3))) unsigned int*)l, 16, 0, 0);
}

// ---- MFMA core: 128x128 tile, BK=64, 4 waves (2x2), XOR-swizzled LDS ----
__device__ __forceinline__ void mfma_core(
    const unsigned short* __restrict__ A0, const unsigned short* __restrict__ A1,
    const unsigned short* __restrict__ W, int ldw, int Ktot,
    int m0, int n0, unsigned short* As, unsigned short* Bs, f32x4 acc[4][4]) {
  int tid = threadIdx.x;
  int lane = tid & 63, w = tid >> 6;
  int wm = w >> 1, wn = w & 1;
  int quad = lane >> 4, c = lane & 15;
  int lrow = lane >> 3;          // 0..7 (row within 8-row staging group)
  int col8 = (lane & 7) ^ lrow;  // source column block after XOR swizzle

  for (int k0 = 0; k0 < Ktot; k0 += 64) {
    const unsigned short* Asrc = (k0 < 1024) ? A0 : A1;
    int ka = k0 & 1023;
#pragma unroll
    for (int j = 0; j < 4; ++j) {
      int row = w * 32 + j * 8 + lrow;  // 0..127 within tile
      gload16(Asrc + (size_t)(m0 + row) * 1024 + ka + col8 * 8, As + w * 2048 + j * 512);
      gload16(W + (size_t)(n0 + row) * ldw + k0 + col8 * 8, Bs + w * 2048 + j * 512);
    }
    __syncthreads();
#pragma unroll
    for (int ks = 0; ks < 2; ++ks) {
      bf16x8 af[4], bfr[4];
#pragma unroll
      for (int i = 0; i < 4; ++i) {
        int ra = wm * 64 + i * 16 + c;
        int pa = (ks * 4 + quad) ^ (ra & 7);
        af[i] = *(const bf16x8*)(As + ra * 64 + pa * 8);
        int rb = wn * 64 + i * 16 + c;
        int pb = (ks * 4 + quad) ^ (rb & 7);
        bfr[i] = *(const bf16x8*)(Bs + rb * 64 + pb * 8);
      }
#pragma unroll
      for (int i = 0; i < 4; ++i)
#pragma unroll
        for (int jn = 0; jn < 4; ++jn)
          acc[i][jn] = __builtin_amdgcn_mfma_f32_16x16x32_bf16(af[i], bfr[jn], acc[i][jn], 0, 0, 0);
    }
    __syncthreads();
  }
}

// ---- GEMM 1: s[m] = sum_n w2[n]*tanh((x@W1^T)[m][n] + b1[n]) ----
__global__ __launch_bounds__(256) void gemm_s(
    const unsigned short* __restrict__ xb, const unsigned short* __restrict__ W1b,
    const float* __restrict__ b1, const float* __restrict__ w2, float* __restrict__ s) {
  __shared__ unsigned short As[128 * 64];
  __shared__ unsigned short Bs[128 * 64];
  f32x4 acc[4][4];
#pragma unroll
  for (int i = 0; i < 4; ++i)
#pragma unroll
    for (int j = 0; j < 4; ++j) acc[i][j] = (f32x4){0.f, 0.f, 0.f, 0.f};
  int m0 = blockIdx.x * 128, n0 = blockIdx.y * 128;
  mfma_core(xb, xb, W1b, 1024, 1024, m0, n0, As, Bs, acc);
  int tid = threadIdx.x, lane = tid & 63, w = tid >> 6;
  int wm = w >> 1, wn = w & 1, quad = lane >> 4, c = lane & 15;
#pragma unroll
  for (int i = 0; i < 4; ++i) {
#pragma unroll
    for (int r = 0; r < 4; ++r) {
      float p = 0.f;
#pragma unroll
      for (int jn = 0; jn < 4; ++jn) {
        int n = n0 + wn * 64 + jn * 16 + c;
        p += w2[n] * tanh_fast(acc[i][jn][r] + b1[n]);
      }
      p += __shfl_xor(p, 1, 64);
      p += __shfl_xor(p, 2, 64);
      p += __shfl_xor(p, 4, 64);
      p += __shfl_xor(p, 8, 64);
      if (c == 0) atomicAdd(&s[m0 + wm * 64 + i * 16 + quad * 4 + r], p);
    }
  }
}

// ---- GEMM 2: out = tanh([q|x] @ Wc^T + bc), K=2048 ----
__global__ __launch_bounds__(256) void gemm_out(
    const unsigned short* __restrict__ qb, const unsigned short* __restrict__ xb,
    const unsigned short* __restrict__ Wcb, const float* __restrict__ bc_,
    float* __restrict__ out) {
  __shared__ unsigned short As[128 * 64];
  __shared__ unsigned short Bs[128 * 64];
  f32x4 acc[4][4];
#pragma unroll
  for (int i = 0; i < 4; ++i)
#pragma unroll
    for (int j = 0; j < 4; ++j) acc[i][j] = (f32x4){0.f, 0.f, 0.f, 0.f};
  int m0 = blockIdx.x * 128, n0 = blockIdx.y * 128;
  mfma_core(qb, xb, Wcb, 2048, 2048, m0, n0, As, Bs, acc);
  int tid = threadIdx.x, lane = tid & 63, w = tid >> 6;
  int wm = w >> 1, wn = w & 1, quad = lane >> 4, c = lane & 15;
#pragma unroll
  for (int i = 0; i < 4; ++i)
#pragma unroll
    for (int jn = 0; jn < 4; ++jn) {
      int n = n0 + wn * 64 + jn * 16 + c;
      float bias = bc_[n];
#pragma unroll
      for (int r = 0; r < 4; ++r) {
        int m = m0 + wm * 64 + i * 16 + quad * 4 + r;
        out[(size_t)m * Dd + n] = tanh_fast(acc[i][jn][r] + bias);
      }
    }
}

// ---- merged cast + zero: x->xb, W1->W1b, Wc->Wcb, s:=0 ----
__global__ __launch_bounds__(256) void cast_all(
    const float4* __restrict__ x, const float4* __restrict__ W1,
    const float4* __restrict__ Wc, ushort4* __restrict__ xb,
    ushort4* __restrict__ W1b, ushort4* __restrict__ Wcb,
    float4* __restrict__ s) {
  int i = blockIdx.x * 256 + threadIdx.x;
  if (i < 8388608) {
    float4 v = x[i];
    ushort4 o;
    o.x = f2bf(v.x); o.y = f2bf(v.y); o.z = f2bf(v.z); o.w = f2bf(v.w);
    xb[i] = o;
  } else if (i < 8650752) {
    int p = i - 8388608;
    float4 v = W1[p];
    ushort4 o;
    o.x = f2bf(v.x); o.y = f2bf(v.y); o.z = f2bf(v.z); o.w = f2bf(v.w);
    W1b[p] = o;
  } else if (i < 9175040) {
    int p = i - 8650752;
    float4 v = Wc[p];
    ushort4 o;
    o.x = f2bf(v.x); o.y = f2bf(v.y); o.z = f2bf(v.z); o.w = f2bf(v.w);
    Wcb[p] = o;
  } else {
    s[i - 9175040] = (float4){0.f, 0.f, 0.f, 0.f};
  }
}

// ---- softmax + cumsum(e): one block/batch, 16 elems/thread, single pass ----
__global__ __launch_bounds__(256) void softmax_scan(
    const float* __restrict__ s, float* __restrict__ e, float* __restrict__ den) {
  int b = blockIdx.x, tid = threadIdx.x;
  int lane = tid & 63, wid = tid >> 6;
  __shared__ float redm[4], wsum[4];
  const float4* sb4 = (const float4*)(s + (size_t)b * Tt);
  float v[16];
#pragma unroll
  for (int j = 0; j < 4; ++j) {
    float4 f = sb4[tid * 4 + j];
    v[j * 4 + 0] = f.x; v[j * 4 + 1] = f.y; v[j * 4 + 2] = f.z; v[j * 4 + 3] = f.w;
  }
  float m = v[0];
#pragma unroll
  for (int j = 1; j < 16; ++j) m = fmaxf(m, v[j]);
#pragma unroll
  for (int off = 32; off > 0; off >>= 1) m = fmaxf(m, __shfl_xor(m, off, 64));
  if (lane == 0) redm[wid] = m;
  __syncthreads();
  m = fmaxf(fmaxf(redm[0], redm[1]), fmaxf(redm[2], redm[3]));
  float ev[16];
  float ls = 0.f;
#pragma unroll
  for (int j = 0; j < 16; ++j) { ev[j] = __expf(v[j] - m); ls += ev[j]; }
  // inclusive wave scan of ls
  float sc = ls;
#pragma unroll
  for (int off = 1; off < 64; off <<= 1) {
    float tt = __shfl_up(sc, off, 64);
    if (lane >= off) sc += tt;
  }
  if (lane == 63) wsum[wid] = sc;
  __syncthreads();
  float woff = 0.f;
#pragma unroll
  for (int w = 0; w < 4; ++w) woff += (w < wid) ? wsum[w] : 0.f;
  float run = sc - ls + woff;  // exclusive prefix for this thread
  float4* eb4 = (float4*)(e + (size_t)b * Tt);
  float4* db4 = (float4*)(den + (size_t)b * Tt);
#pragma unroll
  for (int j = 0; j < 4; ++j) {
    float4 eo, doo;
    run += ev[j * 4 + 0]; eo.x = ev[j * 4 + 0]; doo.x = run;
    run += ev[j * 4 + 1]; eo.y = ev[j * 4 + 1]; doo.y = run;
    run += ev[j * 4 + 2]; eo.z = ev[j * 4 + 2]; doo.z = run;
    run += ev[j * 4 + 3]; eo.w = ev[j * 4 + 3]; doo.w = run;
    eb4[tid * 4 + j] = eo;
    db4[tid * 4 + j] = doo;
  }
}

// ---- scan pass A: chunk partial sums of e*x ----
__global__ __launch_bounds__(1024) void chunk_sums(
    const unsigned short* __restrict__ xb, const float* __restrict__ e,
    float* __restrict__ S) {
  int bc = blockIdx.x;
  int b = bc >> 6, c = bc & 63;
  int d = threadIdx.x;
  const unsigned short* xp = xb + ((size_t)(b * Tt + c * TCH)) * Dd + d;
  const float* eb = e + (size_t)b * Tt + c * TCH;
  float acc = 0.f;
#pragma unroll 8
  for (int t = 0; t < TCH; ++t) acc += eb[t] * bf2f(xp[(size_t)t * Dd]);
  S[((size_t)bc) * Dd + d] = acc;
}

// ---- scan pass B: exclusive prefix over chunks ----
__global__ __launch_bounds__(256) void chunk_prefix(float* __restrict__ S) {
  int idx = blockIdx.x * 256 + threadIdx.x;  // over Bb*Dd = 8192
  int b = idx >> 10, d = idx & 1023;
  float* Sb = S + (size_t)b * NCHUNK * Dd + d;
  float acc = 0.f;
#pragma unroll 8
  for (int c = 0; c < NCHUNK; ++c) {
    float t = Sb[(size_t)c * Dd];
    Sb[(size_t)c * Dd] = acc;
    acc += t;
  }
}

// ---- scan pass C: finish prefix, q = prefix(e*x)/den -> bf16 ----
__global__ __launch_bounds__(1024) void scan_q(
    const unsigned short* __restrict__ xb, const float* __restrict__ e,
    const float* __restrict__ den, const float* __restrict__ S,
    unsigned short* __restrict__ qb) {
  int bc = blockIdx.x;
  int b = bc >> 6, c = bc & 63;
  int d = threadIdx.x;
  int tbase = b * Tt + c * TCH;
  float acc = S[((size_t)bc) * Dd + d];
  const unsigned short* xp = xb + (size_t)tbase * Dd + d;
  const float* eb = e + tbase;
  const float* db = den + tbase;
  unsigned short* qp = qb + (size_t)tbase * Dd + d;
#pragma unroll 4
  for (int t = 0; t < TCH; ++t) {
    acc += eb[t] * bf2f(xp[(size_t)t * Dd]);
    qp[(size_t)t * Dd] = f2bf(acc * __fdividef(1.0f, db[t]));
  }
}

extern "C" void kernel_launch(void* const* d_in, const int* in_sizes, int n_in,
                              void* d_out, int out_size, void* d_ws, size_t ws_size,
                              hipStream_t stream) {
  const float* x  = (const float*)d_in[0];
  const float* W1 = (const float*)d_in[1];
  const float* b1 = (const float*)d_in[2];
  const float* w2 = (const float*)d_in[3];
  // d_in[4] = b2 : cancels under softmax shift invariance
  const float* Wc = (const float*)d_in[5];
  const float* bc = (const float*)d_in[6];
  float* out = (float*)d_out;

  float* ws = (float*)d_ws;
  float* s_buf   = ws;                       // 32768
  float* e_buf   = ws + 32768;               // 32768
  float* den_buf = ws + 65536;               // 32768
  float* S_buf   = ws + 98304;               // 524288
  unsigned short* qb  = (unsigned short*)(ws + 622592);    // 33554432 bf16
  unsigned short* xb  = (unsigned short*)(ws + 17399808);  // 33554432 bf16
  unsigned short* W1b = (unsigned short*)(ws + 34177024);  // 1048576 bf16
  unsigned short* Wcb = (unsigned short*)(ws + 34701312);  // 2097152 bf16

  cast_all<<<35872, 256, 0, stream>>>((const float4*)x, (const float4*)W1,
                                      (const float4*)Wc, (ushort4*)xb,
                                      (ushort4*)W1b, (ushort4*)Wcb,
                                      (float4*)s_buf);

  gemm_s<<<dim3(Mtot / 128, Dd / 128), 256, 0, stream>>>(xb, W1b, b1, w2, s_buf);
  softmax_scan<<<Bb, 256, 0, stream>>>(s_buf, e_buf, den_buf);
  chunk_sums<<<Bb * NCHUNK, 1024, 0, stream>>>(xb, e_buf, S_buf);
  chunk_prefix<<<Bb * Dd / 256, 256, 0, stream>>>(S_buf);
  scan_q<<<Bb * NCHUNK, 1024, 0, stream>>>(xb, e_buf, den_buf, S_buf, qb);
  gemm_out<<<dim3(Mtot / 128, Dd / 128), 256, 0, stream>>>(qb, xb, Wcb, bc, out);
}